// Round 10
// baseline (40.419 us; speedup 1.0000x reference)
//
#include <hip/hip_runtime.h>
#include <hip/hip_bf16.h>

// Problem constants
#define PM 8        // groups
#define PK 4096     // codebook entries per group
#define PD 128      // dim
#define PN 8
#define PH 64
#define PW 64

typedef __attribute__((ext_vector_type(8))) short bf16x8;
typedef __attribute__((ext_vector_type(4))) float f32x4;
typedef __attribute__((ext_vector_type(8))) short short8v;

__device__ inline unsigned short f2bf_rne(float f) {
    unsigned int u = __float_as_uint(f);
    unsigned int r = (u + 0x7FFFu + ((u >> 16) & 1u)) >> 16;
    return (unsigned short)r;
}
__device__ inline float bf2f(unsigned short s) {
    return __uint_as_float(((unsigned int)s) << 16);
}

__device__ inline bf16x8 loadcvt8(const float* __restrict__ p) {
    f32x4 x0 = *(const f32x4*)p;
    f32x4 x1 = *(const f32x4*)(p + 4);
    bf16x8 r;
#pragma unroll
    for (int j = 0; j < 4; ++j) {
        r[j]     = (short)f2bf_rne(x0[j]);
        r[j + 4] = (short)f2bf_rne(x1[j]);
    }
    return r;
}

// ---------------------------------------------------------------------------
// Kernel 1 v3 (unchanged from R5, ~4 us): table[m,k,c] via LDS-staged wq,
// swapped-operand MFMA, packed 8 B stores.
// ---------------------------------------------------------------------------
__global__ __launch_bounds__(256) void build_table(
        const float* __restrict__ codebook,
        const float* __restrict__ wq,
        const float* __restrict__ bq,
        unsigned short* __restrict__ table) {
    __shared__ unsigned short ldsA[2048 * 8];   // 2048 frag-units x 16 B = 32 KB
    __shared__ float lds_bq[PD];
    const int b = blockIdx.x;
    const int m = b & 7;
    const int kt0 = (b >> 3) * 128;
    const int tid = threadIdx.x;
    const int wv = tid >> 6;
    const int l  = tid & 63;
    const int lr = l & 15;
    const int lg = l >> 4;

    const float* cb = codebook + (size_t)m * PK * PD;
    const float* wm = wq + (size_t)m * PD * PD;

    if (tid < PD) lds_bq[tid] = bq[m * PD + tid];

    // Stage wq -> LDS frag-major: unit u = (cs<<4)|(kk<<2)|lg holds
    // wq[cs*16 + slot][kk*32 + lg*8 .. +8) as bf16x8 at slot index.
    {
        const int lr_s = tid & 15;
        const int u0 = (tid >> 4) * 8;
#pragma unroll
        for (int i = 0; i < 8; ++i) {
            const int u  = u0 + i;
            const int cs = u >> 4;
            const int kk = (u >> 2) & 3;
            const int lgs = u & 3;
            bf16x8 v = loadcvt8(wm + (size_t)(cs * 16 + lr_s) * PD + kk * 32 + lgs * 8);
            *(bf16x8*)&ldsA[(size_t)(u * 16 + lr_s) * 8] = v;
        }
    }

    // Codebook B-frags (per-wave k rows), loaded while staging is in flight.
    bf16x8 bfragc[2][4];
#pragma unroll
    for (int ks = 0; ks < 2; ++ks) {
        const int k = kt0 + wv * 32 + ks * 16 + lr;
        const float* src = cb + (size_t)k * PD + lg * 8;
#pragma unroll
        for (int kk = 0; kk < 4; ++kk) {
            bfragc[ks][kk] = loadcvt8(src + kk * 32);
        }
    }
    __syncthreads();

#pragma unroll
    for (int cs = 0; cs < 8; ++cs) {
        bf16x8 afragw[4];
#pragma unroll
        for (int kk = 0; kk < 4; ++kk) {
            const int u = (cs << 4) | (kk << 2) | lg;
            afragw[kk] = *(const bf16x8*)&ldsA[(size_t)(u * 16 + lr) * 8];
        }
        const f32x4 bias4 = *(const f32x4*)&lds_bq[cs * 16 + lg * 4];
#pragma unroll
        for (int ks = 0; ks < 2; ++ks) {
            f32x4 acc = {0.f, 0.f, 0.f, 0.f};
#pragma unroll
            for (int kk = 0; kk < 4; ++kk) {
                acc = __builtin_amdgcn_mfma_f32_16x16x32_bf16(
                        afragw[kk], bfragc[ks][kk], acc, 0, 0, 0);
            }
            // D[row = c = cs*16 + lg*4 + j][col = k = kt0+wv*32+ks*16+lr]
            const int k = kt0 + wv * 32 + ks * 16 + lr;
            unsigned int p0 = (unsigned int)f2bf_rne(acc[0] + bias4[0])
                            | ((unsigned int)f2bf_rne(acc[1] + bias4[1]) << 16);
            unsigned int p1 = (unsigned int)f2bf_rne(acc[2] + bias4[2])
                            | ((unsigned int)f2bf_rne(acc[3] + bias4[3]) << 16);
            uint2 pk; pk.x = p0; pk.y = p1;
            *(uint2*)&table[((size_t)(m * PK + k)) * PD + cs * 16 + lg * 4] = pk;
        }
    }
}

// ---------------------------------------------------------------------------
// Kernel 2 v9: DRAM-row contiguity test — 4 KB back-to-back write spans.
// Every prior variant emitted 256 B chunks hopping between c-planes each
// instruction => ~1 DRAM row visit per 256 B. This version: block =
// (m, n, cs of 16 channels, hg of 16 h); each wave owns 4 c-planes and
// writes, per plane, FOUR consecutive 1 KB store instrs (4 hl x 64 w) =
// one 4 KB contiguous span per row visit. hg is the fastest grid bit so
// consecutive same-XCD blocks extend the same planes' spans.
// Phase 1: thread (w=tid&63, hi2=tid>>6) handles 4 positions; per position:
//   code load + 2x16 B table gathers (32 B c-slice), staged RAW (bf16 pairs
//   as u32) into LDS words [c2][hl][w] — write banks w%32 = 2-way free.
// Phase 2: wave v, lane (hl2=l>>4, wq=l&15): per c-pair b128 LDS read
//   (reused for lo/hi planes), cvt, two f32x4 stores. 1 KB/instr contiguous.
// Totals (bytes, requests) unchanged vs R1 — only write ORDER changes.
// LDS 32 KB; grid 2048 x 256 thr; m = b&7 XCD affinity.
// ---------------------------------------------------------------------------
__global__ __launch_bounds__(256) void gather_scatter(
        const int* __restrict__ codes,
        const unsigned short* __restrict__ table,
        float* __restrict__ out) {
    __shared__ unsigned int ldsW[8 * 16 * 64];   // [c2][hl][w] u32 = 32 KB
    const int b = blockIdx.x;
    const int m  = b & 7;
    const int r  = b >> 3;          // 0..255
    const int hg = r & 3;           // fastest: adjacent blocks extend spans
    const int cs = (r >> 2) & 7;
    const int n  = r >> 5;
    const int tid = threadIdx.x;

    // ---- Phase 1: coop gather, stage bf16-pair words into LDS ----
    {
        const int w   = tid & 63;
        const int hi2 = tid >> 6;   // 0..3
#pragma unroll
        for (int i = 0; i < 4; ++i) {
            const int hl = hi2 * 4 + i;          // 0..15
            const int h  = hg * 16 + hl;
            const int code = codes[((size_t)((n * PH + h) * PW + w)) * PM + m];
            const unsigned short* row =
                table + ((size_t)m * PK + code) * PD + cs * 16;
#pragma unroll
            for (int q = 0; q < 2; ++q) {
                uint4 ch = *(const uint4*)(row + q * 8);
                ldsW[(q * 4 + 0) * 1024 + hl * 64 + w] = ch.x;
                ldsW[(q * 4 + 1) * 1024 + hl * 64 + w] = ch.y;
                ldsW[(q * 4 + 2) * 1024 + hl * 64 + w] = ch.z;
                ldsW[(q * 4 + 3) * 1024 + hl * 64 + w] = ch.w;
            }
        }
    }
    __syncthreads();

    // ---- Phase 2: 1 KB store instrs, 4 back-to-back per 4 KB plane span ----
    const int v   = tid >> 6;       // wave 0..3 -> c2 pairs {2v, 2v+1}
    const int l   = tid & 63;
    const int hl2 = l >> 4;         // 0..3
    const int wq  = l & 15;         // 0..15
#pragma unroll
    for (int cpi = 0; cpi < 2; ++cpi) {
        const int c2l = v * 2 + cpi;          // 0..7
        const int cl0 = 2 * c2l;              // even channel of the pair
        float* p0 = out
            + ((size_t)(n * (PM * PD) + m * PD + cs * 16 + cl0)) * (PH * PW)
            + (hg * 16 + hl2) * PW + wq * 4;
#pragma unroll
        for (int hb = 0; hb < 4; ++hb) {
            const int hl = hb * 4 + hl2;
            uint4 ww = *(const uint4*)&ldsW[c2l * 1024 + hl * 64 + wq * 4];
            f32x4 lo, hi;
            lo[0] = __uint_as_float(ww.x << 16);
            lo[1] = __uint_as_float(ww.y << 16);
            lo[2] = __uint_as_float(ww.z << 16);
            lo[3] = __uint_as_float(ww.w << 16);
            hi[0] = __uint_as_float(ww.x & 0xFFFF0000u);
            hi[1] = __uint_as_float(ww.y & 0xFFFF0000u);
            hi[2] = __uint_as_float(ww.z & 0xFFFF0000u);
            hi[3] = __uint_as_float(ww.w & 0xFFFF0000u);
            float* pb = p0 + (size_t)hb * 4 * PW;          // next 1 KB of span
            *(f32x4*)pb = lo;
            *(f32x4*)(pb + (size_t)(PH * PW)) = hi;        // sibling plane
        }
    }
}

// ---------------------------------------------------------------------------
// Fallback (only if ws_size < table size): fused direct compute, fp32.
// ---------------------------------------------------------------------------
__global__ __launch_bounds__(256) void fused_direct(
        const int* __restrict__ codes,
        const float* __restrict__ codebook,
        const float* __restrict__ wq,
        const float* __restrict__ bq,
        float* __restrict__ out) {
    __shared__ float rows[PW][133];
    const int b = blockIdx.x;
    const int m = b & 7;
    const int rest = b >> 3;
    const int n = rest >> 6;
    const int h = rest & 63;
    const int tid = threadIdx.x;

    for (int idx = tid; idx < PW * 32; idx += 256) {
        const int r = idx >> 5;
        const int e = (idx & 31) * 4;
        const int code = codes[((n * PH + h) * PW + r) * PM + m];
        const float* src = codebook + ((size_t)m * PK + code) * PD + e;
#pragma unroll
        for (int j = 0; j < 4; ++j) rows[r][e + j] = src[j];
    }
    __syncthreads();

    const int w = tid & 63;
    const int cb0 = (tid >> 6) * 32;
    float* ob = out + (((size_t)n * (PM * PD) + m * PD + cb0) * PH + h) * PW + w;
    for (int ci = 0; ci < 32; ++ci) {
        const int c = cb0 + ci;
        const float* wr = wq + ((size_t)m * PD + c) * PD;
        float acc = bq[m * PD + c];
#pragma unroll 4
        for (int d = 0; d < PD; ++d) acc += rows[w][d] * wr[d];
        ob[(size_t)ci * (PH * PW)] = acc;
    }
}

extern "C" void kernel_launch(void* const* d_in, const int* in_sizes, int n_in,
                              void* d_out, int out_size, void* d_ws, size_t ws_size,
                              hipStream_t stream) {
    const int*   codes    = (const int*)  d_in[0];
    const float* codebook = (const float*)d_in[1];
    const float* wq       = (const float*)d_in[2];
    const float* bq       = (const float*)d_in[3];
    float* out = (float*)d_out;

    const size_t table_bytes = (size_t)PM * PK * PD * sizeof(unsigned short); // 8 MB
    if (ws_size >= table_bytes) {
        unsigned short* table = (unsigned short*)d_ws;
        build_table<<<dim3(256), dim3(256), 0, stream>>>(codebook, wq, bq, table);
        gather_scatter<<<dim3(2048), dim3(256), 0, stream>>>(codes, table, out);
    } else {
        fused_direct<<<dim3(PM * PN * PH), dim3(256), 0, stream>>>(codes, codebook, wq, bq, out);
    }
}

// Round 11
// 37.232 us; speedup vs baseline: 1.0856x; 1.0856x over previous
//
#include <hip/hip_runtime.h>
#include <hip/hip_bf16.h>

// Problem constants
#define PM 8        // groups
#define PK 4096     // codebook entries per group
#define PD 128      // dim
#define PN 8
#define PH 64
#define PW 64

typedef __attribute__((ext_vector_type(8))) short bf16x8;
typedef __attribute__((ext_vector_type(4))) float f32x4;
typedef __attribute__((ext_vector_type(8))) short short8v;

__device__ inline unsigned short f2bf_rne(float f) {
    unsigned int u = __float_as_uint(f);
    unsigned int r = (u + 0x7FFFu + ((u >> 16) & 1u)) >> 16;
    return (unsigned short)r;
}
__device__ inline float bf2f(unsigned short s) {
    return __uint_as_float(((unsigned int)s) << 16);
}

__device__ inline bf16x8 loadcvt8(const float* __restrict__ p) {
    f32x4 x0 = *(const f32x4*)p;
    f32x4 x1 = *(const f32x4*)(p + 4);
    bf16x8 r;
#pragma unroll
    for (int j = 0; j < 4; ++j) {
        r[j]     = (short)f2bf_rne(x0[j]);
        r[j + 4] = (short)f2bf_rne(x1[j]);
    }
    return r;
}

// ---------------------------------------------------------------------------
// Kernel 1 v3 (measured-best, ~4 us): table[m,k,c] = sum_d codebook[m,k,d]*
// wq[m,c,d] + bq[m,c] in bf16, via LDS-staged frag-major wq, swapped-operand
// MFMA (D[row=c][col=k] -> lane holds 4 consecutive c -> packed 8 B stores).
// Traffic ~24 MB ≈ fabric-floor for this pass.
// ---------------------------------------------------------------------------
__global__ __launch_bounds__(256) void build_table(
        const float* __restrict__ codebook,
        const float* __restrict__ wq,
        const float* __restrict__ bq,
        unsigned short* __restrict__ table) {
    __shared__ unsigned short ldsA[2048 * 8];   // 2048 frag-units x 16 B = 32 KB
    __shared__ float lds_bq[PD];
    const int b = blockIdx.x;
    const int m = b & 7;
    const int kt0 = (b >> 3) * 128;
    const int tid = threadIdx.x;
    const int wv = tid >> 6;
    const int l  = tid & 63;
    const int lr = l & 15;
    const int lg = l >> 4;

    const float* cb = codebook + (size_t)m * PK * PD;
    const float* wm = wq + (size_t)m * PD * PD;

    if (tid < PD) lds_bq[tid] = bq[m * PD + tid];

    // Stage wq -> LDS frag-major: unit u = (cs<<4)|(kk<<2)|lg holds
    // wq[cs*16 + slot][kk*32 + lg*8 .. +8) as bf16x8 at slot index.
    {
        const int lr_s = tid & 15;
        const int u0 = (tid >> 4) * 8;
#pragma unroll
        for (int i = 0; i < 8; ++i) {
            const int u  = u0 + i;
            const int cs = u >> 4;
            const int kk = (u >> 2) & 3;
            const int lgs = u & 3;
            bf16x8 v = loadcvt8(wm + (size_t)(cs * 16 + lr_s) * PD + kk * 32 + lgs * 8);
            *(bf16x8*)&ldsA[(size_t)(u * 16 + lr_s) * 8] = v;
        }
    }

    // Codebook B-frags (per-wave k rows), loaded while staging is in flight.
    bf16x8 bfragc[2][4];
#pragma unroll
    for (int ks = 0; ks < 2; ++ks) {
        const int k = kt0 + wv * 32 + ks * 16 + lr;
        const float* src = cb + (size_t)k * PD + lg * 8;
#pragma unroll
        for (int kk = 0; kk < 4; ++kk) {
            bfragc[ks][kk] = loadcvt8(src + kk * 32);
        }
    }
    __syncthreads();

#pragma unroll
    for (int cs = 0; cs < 8; ++cs) {
        bf16x8 afragw[4];
#pragma unroll
        for (int kk = 0; kk < 4; ++kk) {
            const int u = (cs << 4) | (kk << 2) | lg;
            afragw[kk] = *(const bf16x8*)&ldsA[(size_t)(u * 16 + lr) * 8];
        }
        const f32x4 bias4 = *(const f32x4*)&lds_bq[cs * 16 + lg * 4];
#pragma unroll
        for (int ks = 0; ks < 2; ++ks) {
            f32x4 acc = {0.f, 0.f, 0.f, 0.f};
#pragma unroll
            for (int kk = 0; kk < 4; ++kk) {
                acc = __builtin_amdgcn_mfma_f32_16x16x32_bf16(
                        afragw[kk], bfragc[ks][kk], acc, 0, 0, 0);
            }
            // D[row = c = cs*16 + lg*4 + j][col = k = kt0+wv*32+ks*16+lr]
            const int k = kt0 + wv * 32 + ks * 16 + lr;
            unsigned int p0 = (unsigned int)f2bf_rne(acc[0] + bias4[0])
                            | ((unsigned int)f2bf_rne(acc[1] + bias4[1]) << 16);
            unsigned int p1 = (unsigned int)f2bf_rne(acc[2] + bias4[2])
                            | ((unsigned int)f2bf_rne(acc[3] + bias4[3]) << 16);
            uint2 pk; pk.x = p0; pk.y = p1;
            *(uint2*)&table[((size_t)(m * PK + k)) * PD + cs * 16 + lg * 4] = pk;
        }
    }
}

// ---------------------------------------------------------------------------
// Kernel 2 v4 (measured-best, ~33 us): out[n, m*128+c, h, w] =
// table[m, codes[n,h,w,m], c]. Lane = w (coalesced 256 B/instr stores),
// 4 waves cover c in chunks of 32; per-lane 16 B table gathers; plain
// stores. m = b&7 keeps each XCD on its 1 MB table slice.
// Moves 134 MB writes + ~70 MB reads = 204 MB at ~6.2 TB/s fabric rate —
// >=95% of the 6.3 TB/s achievable ceiling. Nine structural variants
// (NT stores, wider stores, LDS transpose, coop gather, pipelining,
// DRAM-row ordering) all measured within +-5% of this: byte-conserving
// rearrangements are neutral because the fabric, not the pattern, limits.
// ---------------------------------------------------------------------------
__global__ __launch_bounds__(256) void gather_scatter(
        const int* __restrict__ codes,
        const unsigned short* __restrict__ table,
        float* __restrict__ out) {
    const int b = blockIdx.x;
    const int m = b & 7;
    const int rest = b >> 3;
    const int n = rest >> 6;
    const int h = rest & 63;
    const int tid = threadIdx.x;
    const int w = tid & 63;
    const int cb0 = (tid >> 6) * 32;   // 0,32,64,96 per wave

    const int code = codes[((n * PH + h) * PW + w) * PM + m];
    const unsigned short* row = table + ((size_t)m * PK + code) * PD + cb0;
    float* ob = out + (((size_t)n * (PM * PD) + m * PD + cb0) * PH + h) * PW + w;

#pragma unroll
    for (int i = 0; i < 4; ++i) {
        short8v v = *(const short8v*)(row + i * 8);
#pragma unroll
        for (int j = 0; j < 8; ++j) {
            ob[(size_t)(i * 8 + j) * (PH * PW)] = bf2f((unsigned short)v[j]);
        }
    }
}

// ---------------------------------------------------------------------------
// Fallback (only if ws_size < table size): fused direct compute, fp32.
// ---------------------------------------------------------------------------
__global__ __launch_bounds__(256) void fused_direct(
        const int* __restrict__ codes,
        const float* __restrict__ codebook,
        const float* __restrict__ wq,
        const float* __restrict__ bq,
        float* __restrict__ out) {
    __shared__ float rows[PW][133];
    const int b = blockIdx.x;
    const int m = b & 7;
    const int rest = b >> 3;
    const int n = rest >> 6;
    const int h = rest & 63;
    const int tid = threadIdx.x;

    for (int idx = tid; idx < PW * 32; idx += 256) {
        const int r = idx >> 5;
        const int e = (idx & 31) * 4;
        const int code = codes[((n * PH + h) * PW + r) * PM + m];
        const float* src = codebook + ((size_t)m * PK + code) * PD + e;
#pragma unroll
        for (int j = 0; j < 4; ++j) rows[r][e + j] = src[j];
    }
    __syncthreads();

    const int w = tid & 63;
    const int cb0 = (tid >> 6) * 32;
    float* ob = out + (((size_t)n * (PM * PD) + m * PD + cb0) * PH + h) * PW + w;
    for (int ci = 0; ci < 32; ++ci) {
        const int c = cb0 + ci;
        const float* wr = wq + ((size_t)m * PD + c) * PD;
        float acc = bq[m * PD + c];
#pragma unroll 4
        for (int d = 0; d < PD; ++d) acc += rows[w][d] * wr[d];
        ob[(size_t)ci * (PH * PW)] = acc;
    }
}

extern "C" void kernel_launch(void* const* d_in, const int* in_sizes, int n_in,
                              void* d_out, int out_size, void* d_ws, size_t ws_size,
                              hipStream_t stream) {
    const int*   codes    = (const int*)  d_in[0];
    const float* codebook = (const float*)d_in[1];
    const float* wq       = (const float*)d_in[2];
    const float* bq       = (const float*)d_in[3];
    float* out = (float*)d_out;

    const size_t table_bytes = (size_t)PM * PK * PD * sizeof(unsigned short); // 8 MB
    if (ws_size >= table_bytes) {
        unsigned short* table = (unsigned short*)d_ws;
        build_table<<<dim3(256), dim3(256), 0, stream>>>(codebook, wq, bq, table);
        gather_scatter<<<dim3(PM * PN * PH), dim3(256), 0, stream>>>(codes, table, out);
    } else {
        fused_direct<<<dim3(PM * PN * PH), dim3(256), 0, stream>>>(codes, codebook, wq, bq, out);
    }
}